// Round 3
// baseline (1025.718 us; speedup 1.0000x reference)
//
#include <hip/hip_runtime.h>
#include <stdint.h>

// WinnerCombiner: B=64, L=4096, K=64
#define DECAY   0.6065306597126334f   // f32(e^-0.5), bit-exact vs np reference (absmax 0.0 in r1/r2)

#define B_DIM 64
#define L_DIM 4096
#define K_DIM 64

// 6-level DPP max; full-wave max valid in lane 63 (inputs >= 0, bound_ctrl 0-fill safe)
__device__ __forceinline__ float wave_max_to63(float x) {
    int v;
    v = __builtin_amdgcn_update_dpp(0, __float_as_int(x), 0x111, 0xf, 0xf, true); x = fmaxf(x, __int_as_float(v)); // row_shr:1
    v = __builtin_amdgcn_update_dpp(0, __float_as_int(x), 0x112, 0xf, 0xf, true); x = fmaxf(x, __int_as_float(v)); // row_shr:2
    v = __builtin_amdgcn_update_dpp(0, __float_as_int(x), 0x114, 0xf, 0xf, true); x = fmaxf(x, __int_as_float(v)); // row_shr:4
    v = __builtin_amdgcn_update_dpp(0, __float_as_int(x), 0x118, 0xf, 0xf, true); x = fmaxf(x, __int_as_float(v)); // row_shr:8
    v = __builtin_amdgcn_update_dpp(0, __float_as_int(x), 0x142, 0xf, 0xf, true); x = fmaxf(x, __int_as_float(v)); // row_bcast:15
    v = __builtin_amdgcn_update_dpp(0, __float_as_int(x), 0x143, 0xf, 0xf, true); x = fmaxf(x, __int_as_float(v)); // row_bcast:31
    return x;
}

__device__ __forceinline__ float rdlane_f(float x, int l) {
    return __int_as_float(__builtin_amdgcn_readlane(__float_as_int(x), l));
}

// 8 blocks x 512 threads: 8 waves/block = 2 waves/SIMD (TLP latency-fill).
// Each wave owns one batch chain. Resolve is a short SALU chain; ballot/max-tree
// are precomputed one step ahead (they don't depend on the previous winner).
__global__ __launch_bounds__(512, 1) void k1_seq(const float* __restrict__ d2,
                                                 float* __restrict__ out_idx,
                                                 float* __restrict__ out_vals,
                                                 float* __restrict__ out_w,
                                                 float* __restrict__ out_soma) {
    const int tid  = threadIdx.x;
    const int wid  = tid >> 6;
    const int lane = tid & 63;
    const int b    = (blockIdx.x << 3) + wid;

    const float* p = d2 + ((size_t)b << 18) + lane;      // b*L*K + lane
    float* pw      = out_w + ((size_t)b << 18) + lane;

    // 32-deep register prefetch ring
    float buf[32];
#pragma unroll
    for (int u = 0; u < 32; ++u) buf[u] = p[(size_t)u << 6];

    // t=0: z=0 for all lanes. spec1=spec0 and s_w=63 makes the generic resolve
    // degenerate to a plain first-index argmax of spec0.
    float zd = 0.0f, za = 0.0f;
    float spec0 = __builtin_fmaf(0.5f, zd, buf[0]);      // == d2_0 bitwise
    float spec1 = spec0;
    unsigned M0 = (unsigned)__builtin_amdgcn_readlane(__float_as_int(wave_max_to63(spec0)), 63);
    unsigned long long b0 = __ballot(__float_as_uint(spec0) == M0);
    int s_w = 63;

    float idx_hold = 0.0f, val_hold = 0.0f;

    for (int g = 0; g < 128; ++g) {
        const int base32 = (g & 1) << 5;                 // (t & 63) == base32 + u
#pragma unroll
        for (int u = 0; u < 32; ++u) {
            const int t = (g << 5) + u;

            // ---- resolve w_t: readlane -> unsigned SALU compares (bit-cmp == float-cmp for x>=0) ----
            unsigned su = (unsigned)__builtin_amdgcn_readlane(__float_as_int(spec1), s_w);
            unsigned long long wbit = 1ull << s_w;
            unsigned long long cand = (su > M0) ? wbit : ((su == M0) ? (b0 | wbit) : b0);
            int w = (int)__ffsll((long long)cand) - 1;

            // ---- true z_t (selected with OLD winner s_w) ----
            float z = (lane == s_w) ? za : zd;

            // ---- outputs for step t ----
            float d2v = buf[u];
            float val = rdlane_f(d2v, w);
            pw[(size_t)t << 6] = (lane == w) ? 1.0f : 0.0f;   // coalesced one-hot row
            if (lane == (base32 + u)) { idx_hold = (float)w; val_hold = val; }

            // ---- prefetch d2_{t+32} ----
            int tn = t + 32; if (tn > L_DIM - 1) tn = L_DIM - 1;
            buf[u] = p[(size_t)tn << 6];

            // ---- chain A for step t+1 (independent of w_t until s_w update) ----
            zd = __fmul_rn(z, DECAY);                    // z_{t+1} if lane lost t
            za = __fadd_rn(zd, 1.0f);                    // z_{t+1} if lane won t
            float d2n = buf[(u + 1) & 31];               // d2_{t+1}
            spec0 = __builtin_fmaf(0.5f, zd, d2n);       // == fadd(d2, fmul(.5, zd)) bitwise
            spec1 = __builtin_fmaf(0.5f, za, d2n);
            M0 = (unsigned)__builtin_amdgcn_readlane(__float_as_int(wave_max_to63(spec0)), 63);
            b0 = __ballot(__float_as_uint(spec0) == M0);

            s_w = w;

            // ---- coalesced idx/vals/soma store every 64 steps ----
            if (u == 31 && (g & 1)) {
                size_t o = ((size_t)b << 12) + ((size_t)(g >> 1) << 6) + lane;
                out_idx[o]  = idx_hold;
                out_vals[o] = val_hold;
                out_soma[o] = val_hold;   // w is exactly one-hot in fwd float arith -> soma == vals
            }
        }
    }
}

extern "C" void kernel_launch(void* const* d_in, const int* in_sizes, int n_in,
                              void* d_out, int out_size, void* d_ws, size_t ws_size,
                              hipStream_t stream) {
    (void)in_sizes; (void)n_in; (void)out_size; (void)d_ws; (void)ws_size;

    const float* d2 = (const float*)d_in[0];
    float* out = (float*)d_out;

    const size_t BL = (size_t)B_DIM * L_DIM;          // 262144
    float* out_idx  = out;                            // [B, L]
    float* out_vals = out + BL;                       // [B, L]
    float* out_w    = out + 2 * BL;                   // [B, L, K]
    float* out_soma = out + 2 * BL + BL * K_DIM;      // [B, L]

    hipLaunchKernelGGL(k1_seq, dim3(8), dim3(512), 0, stream,
                       d2, out_idx, out_vals, out_w, out_soma);
}

// Round 5
// 860.891 us; speedup vs baseline: 1.1915x; 1.1915x over previous
//
#include <hip/hip_runtime.h>
#include <stdint.h>

// WinnerCombiner: B=64, L=4096, K=64
#define DECAY   0.6065306597126334f   // f32(e^-0.5); bit-exact vs np reference (absmax 0.0 r1-r3)

#define B_DIM 64
#define L_DIM 4096
#define K_DIM 64

template <int CTRL>
__device__ __forceinline__ int dpp_mov(int x) {
    // old=0, row_mask=0xf, bank_mask=0xf, bound_ctrl=true (0-fill; scores >= 0 so identity-safe)
    return __builtin_amdgcn_update_dpp(0, x, CTRL, 0xf, 0xf, true);
}

// 4-level in-row max: after this, lanes 15/31/47/63 hold the max of their 16-lane row.
__device__ __forceinline__ float rowmax4(float x) {
    x = fmaxf(x, __int_as_float(dpp_mov<0x111>(__float_as_int(x))));  // row_shr:1
    x = fmaxf(x, __int_as_float(dpp_mov<0x112>(__float_as_int(x))));  // row_shr:2
    x = fmaxf(x, __int_as_float(dpp_mov<0x114>(__float_as_int(x))));  // row_shr:4
    x = fmaxf(x, __int_as_float(dpp_mov<0x118>(__float_as_int(x))));  // row_shr:8
    return x;
}

// One step of one chain. All scores >= 0, so unsigned-bit compare == float compare.
// Returns new winner (SGPR); updates zd/za/hold in place.
__device__ __forceinline__ int step_chain(float d2v, int sw, float& zd, float& za,
                                          int lane, int slot, int& hold) {
    float z  = (lane == sw) ? za : zd;                 // z_t selected by w_{t-1}
    float sc = __builtin_fmaf(0.5f, z, d2v);           // true score_t (== fadd(d2, fmul(.5,z)))
    zd = __fmul_rn(z, DECAY);                          // z_{t+1} if lane loses t
    za = __fadd_rn(zd, 1.0f);                          // z_{t+1} if lane wins t
    float r = rowmax4(sc);
    unsigned m0 = (unsigned)__builtin_amdgcn_readlane(__float_as_int(r), 15);
    unsigned m1 = (unsigned)__builtin_amdgcn_readlane(__float_as_int(r), 31);
    unsigned m2 = (unsigned)__builtin_amdgcn_readlane(__float_as_int(r), 47);
    unsigned m3 = (unsigned)__builtin_amdgcn_readlane(__float_as_int(r), 63);
    unsigned ma = m0 > m1 ? m0 : m1;
    unsigned mb = m2 > m3 ? m2 : m3;
    unsigned M  = ma > mb ? ma : mb;                   // true max, in SGPR
    unsigned long long cand = __ballot(__float_as_uint(sc) == M);
    int w = (int)__ffsll((long long)cand) - 1;         // first-index argmax (jnp.argmax tiebreak)
    if (lane == slot) hold = w;
    return w;
}

// K1: 32 blocks x 64 threads = 32 waves on 32 CUs. Each wave interleaves TWO
// independent batch chains (ILP fills dependency stalls; TLP hurt in r3).
// Sole output: idx (as float), coalesced store every 64 steps.
__global__ __launch_bounds__(64) void k1_seq(const float* __restrict__ d2,
                                             float* __restrict__ out_idx) {
    const int lane = threadIdx.x;
    const int bA   = blockIdx.x;
    const int bB   = blockIdx.x + 32;
    const float* pA = d2 + ((size_t)bA << 18) + lane;
    const float* pB = d2 + ((size_t)bB << 18) + lane;

    float bufA[16], bufB[16];
#pragma unroll
    for (int u = 0; u < 16; ++u) {
        bufA[u] = pA[(size_t)u << 6];
        bufB[u] = pB[(size_t)u << 6];
    }

    // t=0: z=0 in all lanes (za==zd==0 makes the w-selection moot)
    float zdA = 0.0f, zaA = 0.0f, zdB = 0.0f, zaB = 0.0f;
    int swA = 63, swB = 63;
    int holdA = 0, holdB = 0;

    for (int g = 0; g < 256; ++g) {
#pragma unroll
        for (int u = 0; u < 16; ++u) {
            const int t    = (g << 4) + u;
            const int slot = ((g & 3) << 4) | u;       // t & 63

            swA = step_chain(bufA[u], swA, zdA, zaA, lane, slot, holdA);
            swB = step_chain(bufB[u], swB, zdB, zaB, lane, slot, holdB);

            // prefetch t+16 (clamped; tail value unused)
            int tn = t + 16; if (tn > L_DIM - 1) tn = L_DIM - 1;
            bufA[u] = pA[(size_t)tn << 6];
            bufB[u] = pB[(size_t)tn << 6];
        }
        if ((g & 3) == 3) {
            size_t oA = ((size_t)bA << 12) + ((size_t)(g >> 2) << 6) + lane;
            size_t oB = ((size_t)bB << 12) + ((size_t)(g >> 2) << 6) + lane;
            out_idx[oA] = (float)holdA;
            out_idx[oB] = (float)holdB;
        }
    }
}

// K2: parallel reconstruction from idx. 1024 blocks x 256 threads (4 waves, one
// 64-step chunk each). w is exactly one-hot in forward float arithmetic
// (fadd(-x,x)=+0 off-winner; winner weight == 1.0 +/- 1ulp), soma == vals.
__global__ __launch_bounds__(256) void k2_par(const float* __restrict__ d2,
                                              const float* __restrict__ in_idx,
                                              float* __restrict__ out_vals,
                                              float* __restrict__ out_w,
                                              float* __restrict__ out_soma) {
    const int wid   = threadIdx.x >> 6;
    const int lane  = threadIdx.x & 63;
    const int chunk = (blockIdx.x << 2) | wid;         // 0..4095
    const int c = chunk & 63;                          // chunk within batch
    const int b = chunk >> 6;                          // batch

    const size_t row0 = ((size_t)b << 12) + ((size_t)c << 6);  // b*L + c*64

    int myidx = (int)in_idx[row0 + lane];              // winner of step row0+lane
    float val = d2[((row0 + (size_t)lane) << 6) + myidx];
    out_vals[row0 + lane] = val;
    out_soma[row0 + lane] = val;

    float* pw = out_w + (row0 << 6) + lane;
#pragma unroll 8
    for (int s = 0; s < 64; ++s) {
        int iw = __builtin_amdgcn_readlane(myidx, s);
        pw[(size_t)s << 6] = (lane == iw) ? 1.0f : 0.0f;
    }
}

extern "C" void kernel_launch(void* const* d_in, const int* in_sizes, int n_in,
                              void* d_out, int out_size, void* d_ws, size_t ws_size,
                              hipStream_t stream) {
    (void)in_sizes; (void)n_in; (void)out_size; (void)d_ws; (void)ws_size;

    const float* d2 = (const float*)d_in[0];
    float* out = (float*)d_out;

    const size_t BL = (size_t)B_DIM * L_DIM;          // 262144
    float* out_idx  = out;                            // [B, L]
    float* out_vals = out + BL;                       // [B, L]
    float* out_w    = out + 2 * BL;                   // [B, L, K]
    float* out_soma = out + 2 * BL + BL * K_DIM;      // [B, L]

    hipLaunchKernelGGL(k1_seq, dim3(32), dim3(64), 0, stream, d2, out_idx);
    hipLaunchKernelGGL(k2_par, dim3(1024), dim3(256), 0, stream,
                       d2, out_idx, out_vals, out_w, out_soma);
}

// Round 6
// 487.060 us; speedup vs baseline: 2.1059x; 1.7675x over previous
//
#include <hip/hip_runtime.h>
#include <stdint.h>

// WinnerCombiner: B=64, L=4096, K=64
#define DECAY   0.6065306597126334f   // f32(e^-0.5); arithmetic bit-exact vs np ref (absmax 0.0 r1-r5)

#define B_DIM 64
#define L_DIM 4096
#define K_DIM 64

template <int CTRL>
__device__ __forceinline__ int dpp_mov(int x) {
    // old=0, row_mask=0xf, bank_mask=0xf, bound_ctrl=true (0-fill; scores >= 0 so safe for max)
    return __builtin_amdgcn_update_dpp(0, x, CTRL, 0xf, 0xf, true);
}

// 6-level DPP max; full-wave max lands in lane 63 (validated: r1/r2 absmax 0.0)
__device__ __forceinline__ float wave_max_to63(float x) {
    x = fmaxf(x, __int_as_float(dpp_mov<0x111>(__float_as_int(x))));  // row_shr:1
    x = fmaxf(x, __int_as_float(dpp_mov<0x112>(__float_as_int(x))));  // row_shr:2
    x = fmaxf(x, __int_as_float(dpp_mov<0x114>(__float_as_int(x))));  // row_shr:4
    x = fmaxf(x, __int_as_float(dpp_mov<0x118>(__float_as_int(x))));  // row_shr:8
    x = fmaxf(x, __int_as_float(dpp_mov<0x142>(__float_as_int(x))));  // row_bcast:15
    x = fmaxf(x, __int_as_float(dpp_mov<0x143>(__float_as_int(x))));  // row_bcast:31
    return x;
}

__device__ __forceinline__ float rdlane_f(float x, int l) {
    return __int_as_float(__builtin_amdgcn_readlane(__float_as_int(x), l));
}

// K1: 64 blocks x 64 threads, 1 wave/chain (r5 lesson: wall = cy/step, use all chains in parallel).
// Pure-VALU step: no SALU crossings, no index math, no per-step stores.
// Output: per-lane 64-bit win mask per 64-step chunk.
__global__ __launch_bounds__(64) void k1_seq(const float* __restrict__ d2,
                                             uint2* __restrict__ wmask) {
    const int lane = threadIdx.x;
    const int b    = blockIdx.x;
    const float* p = d2 + ((size_t)b << 18) + lane;

    float buf[16];
#pragma unroll
    for (int u = 0; u < 16; ++u) buf[u] = p[(size_t)u << 6];

    float z = 0.0f;

    for (int g = 0; g < 64; ++g) {
        unsigned wlo = 0u, whi = 0u;
#pragma unroll
        for (int u = 0; u < 64; ++u) {
            const int t = (g << 6) + u;
            float d2v = buf[u & 15];
            int tn = t + 16; if (tn > L_DIM - 1) tn = L_DIM - 1;   // uniform -> SALU, off-path
            buf[u & 15] = p[(size_t)tn << 6];

            float sc = __builtin_fmaf(0.5f, z, d2v);   // == fadd(d2, fmul(.5,z)) bitwise (proven r3-r5)
            float M  = rdlane_f(wave_max_to63(sc), 63);

            unsigned long long mk = __ballot(sc == M);
            unsigned a = __builtin_amdgcn_mbcnt_lo((unsigned)mk, 0u);
            a = __builtin_amdgcn_mbcnt_hi((unsigned)(mk >> 32), a);
            float h1   = (sc == M) ? 1.0f : 0.0f;
            float hard = (a == 0u) ? h1 : 0.0f;        // exactly the first max lane (jnp.argmax tiebreak)

            z = __fadd_rn(__fmul_rn(z, DECAY), hard);  // mul-then-add, matches reference rounding

            unsigned hb = (__float_as_uint(hard) >> 23) & 1u;  // 1 iff hard==1.0f  (off-path)
            if (u < 32) wlo |= hb << u; else whi |= hb << (u - 32);
        }
        wmask[(((size_t)b << 6) + (size_t)g << 6) + lane] = make_uint2(wlo, whi);
    }
}

// K2: parallel decode + output build. 1024 blocks x 256 threads; wave <-> one 64-step chunk.
// w is exactly one-hot in forward float arithmetic (fadd(-x,x)=+0; winner weight 1.0 +/- 1ulp
// << 2% threshold), so w rows are one-hot and soma == vals (validated r4/r5: absmax 0.0).
__global__ __launch_bounds__(256) void k2_par(const float* __restrict__ d2,
                                              const uint2* __restrict__ wmask,
                                              float* __restrict__ out_idx,
                                              float* __restrict__ out_vals,
                                              float* __restrict__ out_w,
                                              float* __restrict__ out_soma) {
    const int wid   = threadIdx.x >> 6;
    const int lane  = threadIdx.x & 63;
    const int chunk = (blockIdx.x << 2) | wid;             // 0..4095 == (b<<6)|c
    const int c = chunk & 63;
    const int b = chunk >> 6;
    const size_t row0 = ((size_t)b << 12) + ((size_t)c << 6);   // b*L + c*64

    uint2 wb = wmask[((size_t)chunk << 6) + lane];          // lane k's win bits for this chunk

    // decode: winner of step s = lane whose bit s is set (exactly one per step)
    int myw = 0;
#pragma unroll
    for (int s = 0; s < 64; ++s) {
        unsigned bit = (s < 32) ? ((wb.x >> s) & 1u) : ((wb.y >> (s - 32)) & 1u);
        unsigned long long m = __ballot(bit != 0u);
        int w = (int)__ffsll((long long)m) - 1;
        if (lane == s) myw = w;                             // lane s owns step row0+s
    }

    out_idx[row0 + lane] = (float)myw;
    float val = d2[((row0 + (size_t)lane) << 6) + myw];
    out_vals[row0 + lane] = val;
    out_soma[row0 + lane] = val;

    // one-hot w rows, vectorized: 16 x dwordx4 per wave (1 KB/instr)
    float4* pw4 = (float4*)(out_w + (row0 << 6));
    const int sub = lane >> 4;            // which of 4 rows this lane covers
    const int cb  = (lane & 15) << 2;     // channel base (4 channels per lane)
#pragma unroll
    for (int j = 0; j < 16; ++j) {
        const int r0 = j << 2;
        int wa = __builtin_amdgcn_readlane(myw, r0 + 0);
        int wbn = __builtin_amdgcn_readlane(myw, r0 + 1);
        int wc = __builtin_amdgcn_readlane(myw, r0 + 2);
        int wd = __builtin_amdgcn_readlane(myw, r0 + 3);
        int t0 = (sub & 2) ? wc : wa;
        int t1 = (sub & 2) ? wd : wbn;
        int wr = (sub & 1) ? t1 : t0;     // winner of row r0+sub
        float4 v;
        v.x = (cb + 0 == wr) ? 1.0f : 0.0f;
        v.y = (cb + 1 == wr) ? 1.0f : 0.0f;
        v.z = (cb + 2 == wr) ? 1.0f : 0.0f;
        v.w = (cb + 3 == wr) ? 1.0f : 0.0f;
        pw4[(size_t)((r0 + sub) << 4) + (lane & 15)] = v;
    }
}

extern "C" void kernel_launch(void* const* d_in, const int* in_sizes, int n_in,
                              void* d_out, int out_size, void* d_ws, size_t ws_size,
                              hipStream_t stream) {
    (void)in_sizes; (void)n_in; (void)out_size; (void)ws_size;

    const float* d2 = (const float*)d_in[0];
    float* out = (float*)d_out;

    const size_t BL = (size_t)B_DIM * L_DIM;          // 262144
    float* out_idx  = out;                            // [B, L]
    float* out_vals = out + BL;                       // [B, L]
    float* out_w    = out + 2 * BL;                   // [B, L, K]
    float* out_soma = out + 2 * BL + BL * K_DIM;      // [B, L]

    uint2* wmask = (uint2*)d_ws;                      // [4096 chunks][64 lanes] = 2 MB

    hipLaunchKernelGGL(k1_seq, dim3(B_DIM), dim3(64), 0, stream, d2, wmask);
    hipLaunchKernelGGL(k2_par, dim3(1024), dim3(256), 0, stream,
                       d2, wmask, out_idx, out_vals, out_w, out_soma);
}